// Round 9
// baseline (334.204 us; speedup 1.0000x reference)
//
#include <hip/hip_runtime.h>
#include <hip/hip_fp16.h>
#include <math.h>

#define GHH 224
#define GWW 224
#define HW (GHH*GWW)     // 50176
#define BATCH 8
#define RAD 3
#define DIAM 7
#define NPTS 49
#define QC 32
// jbu tiling: 16x32 pixel tile, 256 threads, 1x2 px/thread
#define TH 16
#define TW 32
#define QTH (TH + 2*RAD)    // 22
#define QTW (TW + 2*RAD)    // 38
#define QR 40               // LDS row stride (float4 units)
#define QP 882              // plane stride f4: c*882 mod 8 = {0,2,4,6} -> conflict-free staging writes
#define QPIX (QTH*QTW)      // 836

typedef _Float16 h2 __attribute__((ext_vector_type(2)));
typedef _Float16 v8h __attribute__((ext_vector_type(8)));
typedef float v4f __attribute__((ext_vector_type(4)));

#if defined(__has_builtin)
#if __has_builtin(__builtin_amdgcn_fdot2)
#define HAS_FDOT2 1
#endif
#endif

__device__ __forceinline__ h2 as_h2(float f) { union { float f; h2 h; } u; u.f = f; return u.h; }

__device__ __forceinline__ float dot2acc(float a, float b, float acc) {
#ifdef HAS_FDOT2
    return __builtin_amdgcn_fdot2(as_h2(a), as_h2(b), acc, false);
#else
    union { float f; __half2 h; } ua, ub; ua.f = a; ub.f = b;
    float2 fa = __half22float2(ua.h), fb = __half22float2(ub.h);
    return acc + fa.x * fb.x + fa.y * fb.y;
#endif
}

__device__ __forceinline__ float dot16(const float4& a, const float4& b, float acc) {
    acc = dot2acc(a.x, b.x, acc);
    acc = dot2acc(a.y, b.y, acc);
    acc = dot2acc(a.z, b.z, acc);
    acc = dot2acc(a.w, b.w, acc);
    return acc;
}

__device__ __forceinline__ int refl(int i) {
    if (i < 0) i = -i;
    if (i >= GHH) i = 2 * GHH - 2 - i;
    return i;
}

__device__ __forceinline__ float gelu_fast(float v) {
    float u = 0.7978845608f * v * (1.f + 0.044715f * v * v);
    float e = __expf(2.f * u);
    float th = 1.f - 2.f / (e + 1.f);
    return 0.5f * v * (1.f + th);
}

// ---------------- linear ----------------
__global__ void linear_kernel(const float* __restrict__ x,
                              const float* __restrict__ W,
                              const float* __restrict__ bias,
                              float* __restrict__ f0) {
    int gwave = (blockIdx.x * blockDim.x + threadIdx.x) >> 6;
    int lane = threadIdx.x & 63;
    if (gwave >= BATCH * 972) return;
    int b = gwave / 972, j = gwave % 972;
    const float* xr = x + b * 1000;
    const float* wr = W + j * 1000;
    float s = 0.f;
    for (int k = lane; k < 1000; k += 64)
        s += xr[k] * wr[k];
    #pragma unroll
    for (int off = 32; off; off >>= 1) s += __shfl_down(s, off, 64);
    if (lane == 0) f0[gwave] = s + bias[j];
}

// ---------------- bicubic 18 -> 224 ----------------
__device__ __forceinline__ float cubicw(float d) {
    d = fabsf(d);
    if (d <= 1.f) return ((1.25f * d - 2.25f) * d) * d + 1.f;
    if (d < 2.f)  return ((-0.75f * d + 3.75f) * d - 6.f) * d + 3.f;
    return 0.f;
}

__global__ void bicubic_kernel(const float* __restrict__ f0, float* __restrict__ hr) {
    int idx = blockIdx.x * blockDim.x + threadIdx.x;
    if (idx >= BATCH * 3 * HW) return;
    int w = idx % GWW;
    int h = (idx / GWW) % GHH;
    int bc = idx / HW;
    const float* src = f0 + bc * 18 * 18;
    float xx = (w + 0.5f) * (18.f / 224.f) - 0.5f;
    float yy = (h + 0.5f) * (18.f / 224.f) - 0.5f;
    float fx0 = floorf(xx), fy0 = floorf(yy);
    int x0 = (int)fx0, y0 = (int)fy0;
    float tx = xx - fx0, ty = yy - fy0;
    float wx[4], wy[4];
    int ix[4], iy[4];
    #pragma unroll
    for (int k = 0; k < 4; k++) {
        wx[k] = cubicw(tx - (float)(k - 1));
        wy[k] = cubicw(ty - (float)(k - 1));
        int a = x0 + (k - 1); ix[k] = min(max(a, 0), 17);
        a = y0 + (k - 1);     iy[k] = min(max(a, 0), 17);
    }
    float acc = 0.f;
    #pragma unroll
    for (int ky = 0; ky < 4; ky++) {
        float rowv = 0.f;
        #pragma unroll
        for (int kx = 0; kx < 4; kx++) rowv += wx[kx] * src[iy[ky] * 18 + ix[kx]];
        acc += wy[ky] * rowv;
    }
    hr[idx] = acc;
}

// ---------------- prep: pack w2 (4 stages) into f16 MFMA B-fragments ----------------
// layout: wsB[((stage*64 + lane)*2 + frag)*8 + j], frag0 = out-ch n0, frag1 = n0+16
__global__ void prep_kernel(const float* __restrict__ w2s, __half* __restrict__ wsB) {
    int tid = threadIdx.x;          // 256 = 4 stages x 64 lanes
    int s = tid >> 6, l = tid & 63;
    int n0 = l & 15, kq = l >> 4;
    const float* w2 = w2s + s * 1024;
    __half* dst = wsB + (size_t)tid * 16;
    #pragma unroll
    for (int j = 0; j < 8; j++) {
        dst[j]     = __float2half(w2[n0 * QC + kq * 8 + j]);
        dst[8 + j] = __float2half(w2[(n0 + 16) * QC + kq * 8 + j]);
    }
}

// ---------------- range_proj via MFMA; B-frags prepacked ----------------
__global__ __launch_bounds__(256) void rangeproj_kernel(
    const float* __restrict__ guid,
    const float* __restrict__ w1, const float* __restrict__ b1,
    const __half* __restrict__ wsB, const float* __restrict__ b2,
    float4* __restrict__ q4, int stage) {
    __shared__ __align__(16) char sh1b[4 * 256 * 16];   // 16384 B
    __shared__ __align__(16) char sDb[256 * 80];        // 20480 B
    const int tid = threadIdx.x;
    const int idx = blockIdx.x * 256 + tid;
    const int b = idx / HW, pix = idx % HW;
    float g0 = guid[(b * 3 + 0) * HW + pix];
    float g1 = guid[(b * 3 + 1) * HW + pix];
    float g2 = guid[(b * 3 + 2) * HW + pix];

    float h1[QC];
    #pragma unroll
    for (int k = 0; k < QC; k++) {
        float v = w1[k * 3] * g0 + w1[k * 3 + 1] * g1 + w1[k * 3 + 2] * g2 + b1[k];
        h1[k] = gelu_fast(v);
    }
    #pragma unroll
    for (int k = 0; k < 4; k++) {
        union { _Float16 h[8]; float4 f4; } u;
        #pragma unroll
        for (int j = 0; j < 8; j++) u.h[j] = (_Float16)h1[k * 8 + j];
        *(float4*)(sh1b + k * 4096 + tid * 16) = u.f4;
    }
    __syncthreads();

    const int l = tid & 63, w = tid >> 6;
    const int n0 = l & 15;
    const int kq = l >> 4;
    const int wbase = w * 64;

    const v8h* Bp = (const v8h*)(wsB + ((size_t)stage * 64 + l) * 16);
    v8h B0 = Bp[0], B1 = Bp[1];
    const float bias0 = b2[n0], bias1 = b2[n0 + 16];

    #pragma unroll
    for (int t = 0; t < 4; t++) {
        v8h A = *(const v8h*)(sh1b + kq * 4096 + (wbase + 16 * t + n0) * 16);
        v4f D0 = {0.f, 0.f, 0.f, 0.f}, D1 = {0.f, 0.f, 0.f, 0.f};
        D0 = __builtin_amdgcn_mfma_f32_16x16x32_f16(A, B0, D0, 0, 0, 0);
        D1 = __builtin_amdgcn_mfma_f32_16x16x32_f16(A, B1, D1, 0, 0, 0);
        #pragma unroll
        for (int r = 0; r < 4; r++) {
            int p = wbase + 16 * t + 4 * kq + r;
            _Float16* dst = (_Float16*)(sDb + p * 80);
            dst[n0]      = (_Float16)(D0[r] + bias0);
            dst[n0 + 16] = (_Float16)(D1[r] + bias1);
        }
    }
    __syncthreads();

    size_t gbase = (size_t)blockIdx.x * 1024;
    #pragma unroll
    for (int k2 = 0; k2 < 4; k2++) {
        int t2 = k2 * 256 + tid;
        float4 v = *(const float4*)(sDb + (t2 >> 2) * 80 + (t2 & 3) * 16);
        q4[gbase + t2] = v;
    }
}

// ---------------- fused JBU: 1x2 px/thread, packed-f16 scores, rden-cancel ----------------
// LDS col swizzle: halo col c -> slot (c>>1) + (c&1)*19  => tap reads are lane-stride-1
__global__ __launch_bounds__(256, 2) void jbu_kernel(
    const float4* __restrict__ q4,
    const float* __restrict__ hr,
    float* __restrict__ outF,
    const float* __restrict__ temps,
    const float* __restrict__ sigmas,
    int stage)
{
    __shared__ __align__(16) float4 sq[4 * QP];   // 4*882*16 = 56448 B
    __shared__ __align__(16) float4 sh[QTH * QR]; // 880*16   = 14080 B
    const int tx = threadIdx.x, ty = threadIdx.y;
    const int tid = ty * 16 + tx;
    const int b = blockIdx.z;
    const int h0 = blockIdx.y * TH, w0 = blockIdx.x * TW;

    const bool interior = (h0 >= RAD) && (h0 + TH + RAD <= GHH) &&
                          (w0 >= RAD) && (w0 + TW + RAD <= GWW);

    if (interior) {
        const float4* qb = q4 + ((size_t)(b * HW + (h0 - RAD) * GWW + (w0 - RAD))) * 4;
        for (int i = tid; i < 4 * QPIX; i += 256) {
            int px = i >> 2, c = i & 3;
            int r = px / QTW, cc = px - r * QTW;
            int slot = (cc >> 1) + (cc & 1) * 19;
            sq[c * QP + r * QR + slot] = qb[((size_t)r * GWW + cc) * 4 + c];
        }
        const float* hb = hr + (size_t)b * 3 * HW + (size_t)(h0 - RAD) * GWW + (w0 - RAD);
        for (int i = tid; i < QPIX; i += 256) {
            int r = i / QTW, cc = i - r * QTW;
            int slot = (cc >> 1) + (cc & 1) * 19;
            size_t base = (size_t)r * GWW + cc;
            sh[r * QR + slot] = make_float4(hb[base], hb[base + HW], hb[base + 2 * HW], 0.f);
        }
    } else {
        for (int i = tid; i < 4 * QPIX; i += 256) {
            int px = i >> 2, c = i & 3;
            int r = px / QTW, cc = px - r * QTW;
            int slot = (cc >> 1) + (cc & 1) * 19;
            int gh = refl(h0 - RAD + r);
            int gw = refl(w0 - RAD + cc);
            sq[c * QP + r * QR + slot] = q4[(size_t)(b * HW + gh * GWW + gw) * 4 + c];
        }
        for (int i = tid; i < QPIX; i += 256) {
            int r = i / QTW, cc = i - r * QTW;
            int slot = (cc >> 1) + (cc & 1) * 19;
            int gh = refl(h0 - RAD + r);
            int gw = refl(w0 - RAD + cc);
            size_t base = (size_t)b * 3 * HW + (size_t)gh * GWW + gw;
            sh[r * QR + slot] = make_float4(hr[base], hr[base + HW], hr[base + 2 * HW], 0.f);
        }
    }
    __syncthreads();

    // centers: px0 halo col 2tx+3 -> slot tx+20 ; px1 halo col 2tx+4 -> slot tx+2
    float4 A0[4], A1[4];
    {
        int rbc = (ty + RAD) * QR;
        #pragma unroll
        for (int c = 0; c < 4; c++) {
            A0[c] = sq[c * QP + rbc + tx + 20];
            A1[c] = sq[c * QP + rbc + tx + 2];
        }
    }

    // union-tap slot offsets: slot = tx + SOFF[dj], dj = 0..7
    // phase 1: scores, packed (px0, px1) f16 pairs; track raw max in f32
    h2 spair[NPTS];
    float mraw = -1e30f;
    #pragma unroll
    for (int di = 0; di < DIAM; di++) {
        const int rb = (ty + di) * QR;
        float carry = 0.f;
        #pragma unroll
        for (int dj = 0; dj < 8; dj++) {
            const int SOFF = (dj >> 1) + (dj & 1) * 19;   // 0,19,1,20,2,21,3,22
            const int ni = rb + tx + SOFF;
            float a0 = 0.f, a1 = 0.f;
            #pragma unroll
            for (int c = 0; c < 4; c++) {
                float4 v = sq[c * QP + ni];
                if (dj < 7) a0 = dot16(A0[c], v, a0);
                if (dj > 0) a1 = dot16(A1[c], v, a1);
            }
            if (dj < 7) mraw = fmaxf(mraw, a0);
            if (dj > 0) {
                mraw = fmaxf(mraw, a1);
                h2 pr; pr.x = (_Float16)carry; pr.y = (_Float16)a1;
                spair[di * 7 + dj - 1] = pr;
            }
            carry = a0;
        }
    }

    float t = __expf(temps[stage]);
    t = fminf(fmaxf(t, 1e-4f), 1e4f);
    float m = t * mraw;
    float sig = sigmas[stage];
    float inv2s2 = 1.f / (2.f * sig * sig);
    float sd[DIAM];
    #pragma unroll
    for (int i = 0; i < DIAM; i++) {
        float d = (float)(i - 3) * (1.f / 3.f);
        sd[i] = __expf(-d * d * inv2s2);
    }

    // phase 2: out = sum(e*spat*hr) / max(sum(e*spat), 1e-7*sum(e))   [rden cancels]
    float n00 = 0.f, n01 = 0.f, n02 = 0.f, ws0 = 0.f, es0 = 0.f;
    float n10 = 0.f, n11 = 0.f, n12 = 0.f, ws1 = 0.f, es1 = 0.f;
    #pragma unroll
    for (int di = 0; di < DIAM; di++) {
        const int rb = (ty + di) * QR;
        const float sy = sd[di];
        #pragma unroll
        for (int dj = 0; dj < 8; dj++) {
            const int SOFF = (dj >> 1) + (dj & 1) * 19;
            float4 hv = sh[rb + tx + SOFF];
            if (dj < 7) {
                float sv = (float)spair[di * 7 + dj].x;
                float e = __expf(fmaf(t, sv, -m));
                float w = e * sy * sd[dj];
                es0 += e; ws0 += w;
                n00 += w * hv.x; n01 += w * hv.y; n02 += w * hv.z;
            }
            if (dj > 0) {
                float sv = (float)spair[di * 7 + dj - 1].y;
                float e = __expf(fmaf(t, sv, -m));
                float w = e * sy * sd[dj - 1];
                es1 += e; ws1 += w;
                n10 += w * hv.x; n11 += w * hv.y; n12 += w * hv.z;
            }
        }
    }
    float r0 = 1.f / fmaxf(ws0, 1e-7f * es0);
    float r1 = 1.f / fmaxf(ws1, 1e-7f * es1);

    size_t obase = (size_t)b * 3 * HW + (size_t)(h0 + ty) * GWW + (w0 + 2 * tx);
    *(float2*)&outF[obase]          = make_float2(n00 * r0, n10 * r1);
    *(float2*)&outF[obase + HW]     = make_float2(n01 * r0, n11 * r1);
    *(float2*)&outF[obase + 2 * HW] = make_float2(n02 * r0, n12 * r1);
}

extern "C" void kernel_launch(void* const* d_in, const int* in_sizes, int n_in,
                              void* d_out, int out_size, void* d_ws, size_t ws_size,
                              hipStream_t stream) {
    const float* x      = (const float*)d_in[0];
    const float* guid   = (const float*)d_in[1];
    const float* lw     = (const float*)d_in[2];
    const float* lb     = (const float*)d_in[3];
    const float* w1s    = (const float*)d_in[4];
    const float* b1s    = (const float*)d_in[5];
    const float* w2s    = (const float*)d_in[6];
    const float* b2s    = (const float*)d_in[7];
    const float* temps  = (const float*)d_in[8];
    const float* sigmas = (const float*)d_in[9];

    char* ws = (char*)d_ws;
    const size_t Q_BYTES = (size_t)BATCH * HW * QC * sizeof(__half);  // 25,690,112
    const size_t F_BYTES = (size_t)BATCH * 3 * HW * sizeof(float);    //  4,816,896
    float4* q4  = (float4*)ws;
    float* hrA  = (float*)(ws + Q_BYTES);
    float* hrB  = (float*)(ws + Q_BYTES + F_BYTES);
    float* f0   = (float*)(ws + Q_BYTES + 2 * F_BYTES);               // 31,104 B
    __half* wsB = (__half*)(ws + Q_BYTES + 2 * F_BYTES + 31104);      //  8,192 B

    prep_kernel<<<1, 256, 0, stream>>>(w2s, wsB);
    linear_kernel<<<1944, 256, 0, stream>>>(x, lw, lb, f0);
    bicubic_kernel<<<(BATCH * 3 * HW + 255) / 256, 256, 0, stream>>>(f0, hrA);

    dim3 jgrid(GWW / TW, GHH / TH, BATCH), jblock(16, 16);
    const float* hins[4]  = { hrA, hrB, hrA, hrB };
    float*       fouts[4] = { hrB, hrA, hrB, (float*)d_out };
    for (int s = 0; s < 4; s++) {
        rangeproj_kernel<<<(BATCH * HW) / 256, 256, 0, stream>>>(
            guid, w1s + s * 96, b1s + s * 32, wsB, b2s + s * 32, q4, s);
        jbu_kernel<<<jgrid, jblock, 0, stream>>>(
            q4, hins[s], fouts[s], temps, sigmas, s);
    }
}

// Round 10
// 324.821 us; speedup vs baseline: 1.0289x; 1.0289x over previous
//
#include <hip/hip_runtime.h>
#include <hip/hip_fp16.h>
#include <math.h>

#define GHH 224
#define GWW 224
#define HW (GHH*GWW)     // 50176
#define BATCH 8
#define RAD 3
#define DIAM 7
#define NPTS 49
#define QC 32
#define TILE 16
#define TP (TILE + 2*RAD)   // 22
#define TPIX (TP*TP)        // 484
#define CS 485              // chunk-plane stride in float4 (R8-proven layout)
#define SHP 2112            // sH plane stride bytes (128 px * 16 B + 64 pad)

typedef _Float16 h2 __attribute__((ext_vector_type(2)));
typedef _Float16 v8h __attribute__((ext_vector_type(8)));
typedef float v4f __attribute__((ext_vector_type(4)));

#if defined(__has_builtin)
#if __has_builtin(__builtin_amdgcn_fdot2)
#define HAS_FDOT2 1
#endif
#endif

__device__ __forceinline__ h2 as_h2(float f) { union { float f; h2 h; } u; u.f = f; return u.h; }

__device__ __forceinline__ float dot2acc(float a, float b, float acc) {
#ifdef HAS_FDOT2
    return __builtin_amdgcn_fdot2(as_h2(a), as_h2(b), acc, false);
#else
    union { float f; __half2 h; } ua, ub; ua.f = a; ub.f = b;
    float2 fa = __half22float2(ua.h), fb = __half22float2(ub.h);
    return acc + fa.x * fb.x + fa.y * fb.y;
#endif
}

__device__ __forceinline__ float dot16(const float4& a, const float4& b, float acc) {
    acc = dot2acc(a.x, b.x, acc);
    acc = dot2acc(a.y, b.y, acc);
    acc = dot2acc(a.z, b.z, acc);
    acc = dot2acc(a.w, b.w, acc);
    return acc;
}

__device__ __forceinline__ int refl(int i) {
    if (i < 0) i = -i;
    if (i >= GHH) i = 2 * GHH - 2 - i;
    return i;
}

__device__ __forceinline__ float gelu_fast(float v) {
    float u = 0.7978845608f * v * (1.f + 0.044715f * v * v);
    float e = __expf(2.f * u);
    float th = 1.f - 2.f / (e + 1.f);
    return 0.5f * v * (1.f + th);
}

// ---------------- linear ----------------
__global__ void linear_kernel(const float* __restrict__ x,
                              const float* __restrict__ W,
                              const float* __restrict__ bias,
                              float* __restrict__ f0) {
    int gwave = (blockIdx.x * blockDim.x + threadIdx.x) >> 6;
    int lane = threadIdx.x & 63;
    if (gwave >= BATCH * 972) return;
    int b = gwave / 972, j = gwave % 972;
    const float* xr = x + b * 1000;
    const float* wr = W + j * 1000;
    float s = 0.f;
    for (int k = lane; k < 1000; k += 64)
        s += xr[k] * wr[k];
    #pragma unroll
    for (int off = 32; off; off >>= 1) s += __shfl_down(s, off, 64);
    if (lane == 0) f0[gwave] = s + bias[j];
}

// ---------------- bicubic 18 -> 224 ----------------
__device__ __forceinline__ float cubicw(float d) {
    d = fabsf(d);
    if (d <= 1.f) return ((1.25f * d - 2.25f) * d) * d + 1.f;
    if (d < 2.f)  return ((-0.75f * d + 3.75f) * d - 6.f) * d + 3.f;
    return 0.f;
}

__global__ void bicubic_kernel(const float* __restrict__ f0, float* __restrict__ hr) {
    int idx = blockIdx.x * blockDim.x + threadIdx.x;
    if (idx >= BATCH * 3 * HW) return;
    int w = idx % GWW;
    int h = (idx / GWW) % GHH;
    int bc = idx / HW;
    const float* src = f0 + bc * 18 * 18;
    float xx = (w + 0.5f) * (18.f / 224.f) - 0.5f;
    float yy = (h + 0.5f) * (18.f / 224.f) - 0.5f;
    float fx0 = floorf(xx), fy0 = floorf(yy);
    int x0 = (int)fx0, y0 = (int)fy0;
    float tx = xx - fx0, ty = yy - fy0;
    float wx[4], wy[4];
    int ix[4], iy[4];
    #pragma unroll
    for (int k = 0; k < 4; k++) {
        wx[k] = cubicw(tx - (float)(k - 1));
        wy[k] = cubicw(ty - (float)(k - 1));
        int a = x0 + (k - 1); ix[k] = min(max(a, 0), 17);
        a = y0 + (k - 1);     iy[k] = min(max(a, 0), 17);
    }
    float acc = 0.f;
    #pragma unroll
    for (int ky = 0; ky < 4; ky++) {
        float rowv = 0.f;
        #pragma unroll
        for (int kx = 0; kx < 4; kx++) rowv += wx[kx] * src[iy[ky] * 18 + ix[kx]];
        acc += wy[ky] * rowv;
    }
    hr[idx] = acc;
}

// ---------------- prep: pack w2 (4 stages) into f16 MFMA B-fragments ----------------
__global__ void prep_kernel(const float* __restrict__ w2s, __half* __restrict__ wsB) {
    int tid = threadIdx.x;          // 256 = 4 stages x 64 lanes
    int s = tid >> 6, l = tid & 63;
    int n0 = l & 15, kq = l >> 4;
    const float* w2 = w2s + s * 1024;
    __half* dst = wsB + (size_t)tid * 16;
    #pragma unroll
    for (int j = 0; j < 8; j++) {
        dst[j]     = __float2half(w2[n0 * QC + kq * 8 + j]);
        dst[8 + j] = __float2half(w2[(n0 + 16) * QC + kq * 8 + j]);
    }
}

// ---------------- fully fused JBU: in-block range_proj (MFMA) + scores + softmax + conv ----------------
__global__ __launch_bounds__(256, 3) void jbu_kernel(
    const float* __restrict__ guid,
    const float* __restrict__ w1, const float* __restrict__ b1,
    const __half* __restrict__ wsB, const float* __restrict__ b2,
    const float* __restrict__ hr,
    float* __restrict__ outF,
    const float* __restrict__ temps,
    const float* __restrict__ sigmas,
    int stage)
{
    __shared__ __align__(16) float4 sq[4 * CS];     // 31040 B, q tile f16 chunk-planar
    __shared__ __align__(16) float4 sh[TPIX];       //  7744 B, hr tile (3ch + pad)
    __shared__ __align__(16) char   sH[4 * SHP];    //  8448 B, h1 round scratch (4 planes)
    const int tx = threadIdx.x, ty = threadIdx.y;
    const int tid = ty * TILE + tx;
    const int b = blockIdx.z;
    const int h0 = blockIdx.y * TILE, w0 = blockIdx.x * TILE;

    // ---- stage hr tile (loads issued early, overlap with phase 0) ----
    const bool interior = (h0 >= RAD) && (h0 + TILE + RAD <= GHH) &&
                          (w0 >= RAD) && (w0 + TILE + RAD <= GWW);
    if (interior) {
        const float* hb = hr + (size_t)b * 3 * HW + (size_t)(h0 - RAD) * GWW + (w0 - RAD);
        for (int i = tid; i < TPIX; i += 256) {
            int r = i / TP, cx = i % TP;
            size_t base = (size_t)r * GWW + cx;
            sh[i] = make_float4(hb[base], hb[base + HW], hb[base + 2 * HW], 0.f);
        }
    } else {
        for (int i = tid; i < TPIX; i += 256) {
            int r = i / TP, cx = i % TP;
            int gh = refl(h0 - RAD + r);
            int gw = refl(w0 - RAD + cx);
            size_t base = (size_t)b * 3 * HW + (size_t)gh * GWW + gw;
            sh[i] = make_float4(hr[base], hr[base + HW], hr[base + 2 * HW], 0.f);
        }
    }

    // ---- phase 0: compute q tile (layer1 VALU + layer2 MFMA), 4 rounds x 128 px ----
    const int w = tid >> 6, l = tid & 63;
    const int n0 = l & 15, kq = l >> 4;
    const v8h* Bp = (const v8h*)(wsB + ((size_t)stage * 64 + l) * 16);
    const v8h B0 = Bp[0], B1 = Bp[1];
    const float bias0 = b2[n0], bias1 = b2[n0 + 16];
    const int half = w & 1;                 // wave-uniform -> w1/b1 stay s_loads
    const int pxr = ((w >> 1) << 6) + l;    // 0..127 within round

    #pragma unroll 1
    for (int round = 0; round < 4; round++) {
        int px = round * 128 + pxr;
        union { _Float16 h[8]; float4 f4; } pk0, pk1;
        if (px < TPIX) {
            int r = px / TP, c = px - r * TP;
            int gh = refl(h0 - RAD + r), gw = refl(w0 - RAD + c);
            const float* gp = guid + (size_t)(b * 3) * HW + (size_t)gh * GWW + gw;
            float g0 = gp[0], g1 = gp[HW], g2 = gp[2 * HW];
            #pragma unroll
            for (int kk = 0; kk < 8; kk++) {
                int ch = half * 16 + kk;
                float v = w1[ch * 3] * g0 + w1[ch * 3 + 1] * g1 + w1[ch * 3 + 2] * g2 + b1[ch];
                pk0.h[kk] = (_Float16)gelu_fast(v);
            }
            #pragma unroll
            for (int kk = 0; kk < 8; kk++) {
                int ch = half * 16 + 8 + kk;
                float v = w1[ch * 3] * g0 + w1[ch * 3 + 1] * g1 + w1[ch * 3 + 2] * g2 + b1[ch];
                pk1.h[kk] = (_Float16)gelu_fast(v);
            }
        } else {
            pk0.f4 = make_float4(0.f, 0.f, 0.f, 0.f);
            pk1.f4 = make_float4(0.f, 0.f, 0.f, 0.f);
        }
        *(float4*)(sH + (half * 2) * SHP + pxr * 16)     = pk0.f4;
        *(float4*)(sH + (half * 2 + 1) * SHP + pxr * 16) = pk1.f4;
        __syncthreads();
        #pragma unroll
        for (int tt = 0; tt < 2; tt++) {
            int mb = w * 32 + tt * 16;
            v8h A = *(const v8h*)(sH + kq * SHP + (mb + n0) * 16);
            v4f D0 = {0.f, 0.f, 0.f, 0.f}, D1 = {0.f, 0.f, 0.f, 0.f};
            D0 = __builtin_amdgcn_mfma_f32_16x16x32_f16(A, B0, D0, 0, 0, 0);
            D1 = __builtin_amdgcn_mfma_f32_16x16x32_f16(A, B1, D1, 0, 0, 0);
            #pragma unroll
            for (int r = 0; r < 4; r++) {
                int g = round * 128 + mb + 4 * kq + r;   // C/D row = pixel (m89 mapping)
                if (g < TPIX) {
                    *(_Float16*)((char*)sq + ((size_t)(n0 >> 3) * CS + g) * 16 + (n0 & 7) * 2)
                        = (_Float16)(D0[r] + bias0);
                    *(_Float16*)((char*)sq + ((size_t)((n0 >> 3) + 2) * CS + g) * 16 + (n0 & 7) * 2)
                        = (_Float16)(D1[r] + bias1);
                }
            }
        }
        __syncthreads();
    }

    // ---- phase 1: scores (R8-proven structure, 1 px/thread) ----
    int ci = (ty + RAD) * TP + tx + RAD;
    float4 c0 = sq[ci], c1 = sq[CS + ci], c2 = sq[2 * CS + ci], c3 = sq[3 * CS + ci];

    float s[NPTS];
    int p = 0;
    #pragma unroll
    for (int di = 0; di < DIAM; di++) {
        int rb = (ty + di) * TP + tx;
        #pragma unroll
        for (int dj = 0; dj < DIAM; dj++, p++) {
            int ni = rb + dj;
            float acc = dot16(c0, sq[ni], 0.f);
            acc = dot16(c1, sq[CS + ni], acc);
            acc = dot16(c2, sq[2 * CS + ni], acc);
            acc = dot16(c3, sq[3 * CS + ni], acc);
            s[p] = acc;
        }
    }

    // ---- softmax * spatial, renormalize ----
    float t = __expf(temps[stage]);
    t = fminf(fmaxf(t, 1e-4f), 1e4f);
    float sig = sigmas[stage];
    float inv2s2 = 1.f / (2.f * sig * sig);
    float m = -1e30f;
    #pragma unroll
    for (int p2 = 0; p2 < NPTS; p2++) { s[p2] *= t; m = fmaxf(m, s[p2]); }
    float den = 0.f;
    #pragma unroll
    for (int p2 = 0; p2 < NPTS; p2++) { s[p2] = __expf(s[p2] - m); den += s[p2]; }
    float rden = 1.f / den;
    float ksum = 0.f;
    #pragma unroll
    for (int p2 = 0; p2 < NPTS; p2++) {
        int di = p2 / 7, dj = p2 % 7;
        float dy = (float)(di - 3) * (1.f / 3.f);
        float dx = (float)(dj - 3) * (1.f / 3.f);
        float spat = __expf(-(dy * dy + dx * dx) * inv2s2);
        s[p2] = s[p2] * rden * spat;
        ksum += s[p2];
    }
    float rk = 1.f / fmaxf(ksum, 1e-7f);

    // ---- adaptive conv from sh ----
    float o0 = 0.f, o1 = 0.f, o2 = 0.f;
    p = 0;
    #pragma unroll
    for (int di = 0; di < DIAM; di++) {
        int rb = (ty + di) * TP + tx;
        #pragma unroll
        for (int dj = 0; dj < DIAM; dj++, p++) {
            float4 hv = sh[rb + dj];
            float kp = s[p] * rk;
            o0 += kp * hv.x;
            o1 += kp * hv.y;
            o2 += kp * hv.z;
        }
    }
    size_t obase = (size_t)b * 3 * HW + (size_t)(h0 + ty) * GWW + (w0 + tx);
    outF[obase]          = o0;
    outF[obase + HW]     = o1;
    outF[obase + 2 * HW] = o2;
}

extern "C" void kernel_launch(void* const* d_in, const int* in_sizes, int n_in,
                              void* d_out, int out_size, void* d_ws, size_t ws_size,
                              hipStream_t stream) {
    const float* x      = (const float*)d_in[0];
    const float* guid   = (const float*)d_in[1];
    const float* lw     = (const float*)d_in[2];
    const float* lb     = (const float*)d_in[3];
    const float* w1s    = (const float*)d_in[4];
    const float* b1s    = (const float*)d_in[5];
    const float* w2s    = (const float*)d_in[6];
    const float* b2s    = (const float*)d_in[7];
    const float* temps  = (const float*)d_in[8];
    const float* sigmas = (const float*)d_in[9];

    char* ws = (char*)d_ws;
    const size_t F_BYTES = (size_t)BATCH * 3 * HW * sizeof(float);    //  4,816,896
    float* hrA  = (float*)ws;
    float* hrB  = (float*)(ws + F_BYTES);
    float* f0   = (float*)(ws + 2 * F_BYTES);                         // 31,104 B
    __half* wsB = (__half*)(ws + 2 * F_BYTES + 31104);                //  8,192 B

    prep_kernel<<<1, 256, 0, stream>>>(w2s, wsB);
    linear_kernel<<<1944, 256, 0, stream>>>(x, lw, lb, f0);
    bicubic_kernel<<<(BATCH * 3 * HW + 255) / 256, 256, 0, stream>>>(f0, hrA);

    dim3 jgrid(14, 14, BATCH), jblock(16, 16);
    const float* hins[4]  = { hrA, hrB, hrA, hrB };
    float*       fouts[4] = { hrB, hrA, hrB, (float*)d_out };
    for (int s = 0; s < 4; s++) {
        jbu_kernel<<<jgrid, jblock, 0, stream>>>(
            guid, w1s + s * 96, b1s + s * 32, wsB, b2s + s * 32,
            hins[s], fouts[s], temps, sigmas, s);
    }
}